// Round 2
// baseline (141.495 us; speedup 1.0000x reference)
//
#include <hip/hip_runtime.h>

// Problem constants (from reference): B=32, T=1024, D=1024, N_ITER=256, SR=4
#define BB 32
#define TT 1024
#define DD 1024
#define NIT 256
#define SRR 4
#define CS 32            // ODE steps per staged chunk
#define K1T 128          // threads (= t values) per gw_ode block
#define KT 16            // t values per cubic block

// ---------------------------------------------------------------------------
// Kernel 1: warp-function ODE. Block = 128 consecutive t of one b.
// Stage ds[b, t0..t0+128, c*32..c*32+31] into LDS (coalesced 128B row-chunks,
// stride-33 padding = conflict-free), register-double-buffered across chunks.
// Fast path keeps g = f - r0 with a single fma + clamp per step; a per-lane
// 'bad' flag falls back to the exact general gather integration (never taken
// for the bench data, exec-mask-skipped).
// ---------------------------------------------------------------------------
__global__ __launch_bounds__(K1T) void gw_ode_kernel(const float* __restrict__ ds,
                                                     float* __restrict__ f_out) {
    __shared__ float slab[(K1T + 1) * 33];     // [129][33] floats, 17 KB
    const int tid = threadIdx.x;
    const int b   = blockIdx.x >> 3;           // 8 blocks per b
    const int t0  = (blockIdx.x & 7) * K1T;
    const int t   = t0 + tid;
    const int r0  = (t < TT - 2) ? t : (TT - 2);
    const int ia  = r0 - t0;                   // slab row of d0 for this lane
    const float inv = 1.0f / (float)(NIT * SRR);
    const float lo  = -(float)r0;
    const float hi  = (float)(TT - 1 - r0);
    const bool edge = (r0 == TT - 2);

    const float4* dsv = (const float4*)ds;

    float4 buf[2][9];
    // prologue: issue chunk-0 loads (8 float4/thread + 8-lane tail row)
#pragma unroll
    for (int it = 0; it < 8; ++it) {
        const int p = it * K1T + tid, r = p >> 3, q = p & 7;
        const int row = (t0 + r < TT - 1) ? (t0 + r) : (TT - 1);
        buf[0][it] = dsv[(size_t)(b * TT + row) * (NIT / 4) + q];
    }
    if (tid < 8) {
        const int row = (t0 + K1T < TT - 1) ? (t0 + K1T) : (TT - 1);
        buf[0][8] = dsv[(size_t)(b * TT + row) * (NIT / 4) + tid];
    }

    float g = 0.0f;
    bool bad = false;

#pragma unroll
    for (int c = 0; c < NIT / CS; ++c) {
        if (c > 0) __syncthreads();            // all lanes done with prev slab
        // registers -> LDS (conflict-free: (r + 4q + m) spreads banks)
#pragma unroll
        for (int it = 0; it < 8; ++it) {
            const int p = it * K1T + tid, r = p >> 3, q = p & 7;
            const float4 v = buf[c & 1][it];
            float* s = slab + r * 33 + q * 4;
            s[0] = v.x; s[1] = v.y; s[2] = v.z; s[3] = v.w;
        }
        if (tid < 8) {
            const float4 v = buf[c & 1][8];
            float* s = slab + K1T * 33 + tid * 4;
            s[0] = v.x; s[1] = v.y; s[2] = v.z; s[3] = v.w;
        }
        __syncthreads();
        // issue next chunk's loads; latency hides under the 32 ODE steps
        if (c < NIT / CS - 1) {
#pragma unroll
            for (int it = 0; it < 8; ++it) {
                const int p = it * K1T + tid, r = p >> 3, q = p & 7;
                const int row = (t0 + r < TT - 1) ? (t0 + r) : (TT - 1);
                buf[(c + 1) & 1][it] =
                    dsv[(size_t)(b * TT + row) * (NIT / 4) + (c + 1) * (CS / 4) + q];
            }
            if (tid < 8) {
                const int row = (t0 + K1T < TT - 1) ? (t0 + K1T) : (TT - 1);
                buf[(c + 1) & 1][8] =
                    dsv[(size_t)(b * TT + row) * (NIT / 4) + (c + 1) * (CS / 4) + tid];
            }
        }
        // consume 32 steps
        int jstart = 0;
        if (c == 0) {
            float f0 = (float)t + slab[tid * 33] * inv;      // ds[b,t,0]
            f0 = fminf(fmaxf(f0, 0.0f), (float)(TT - 1));
            g = f0 - (float)r0;
            jstart = 1;
        }
#pragma unroll 8
        for (int j = jstart; j < CS; ++j) {
            const float d0 = slab[ia * 33 + j] * inv;
            const float d1 = slab[(ia + 1) * 33 + j] * inv;
            g = fmaf(g, 1.0f + (d1 - d0), d0);               // 1-fma chain
            g = fminf(fmaxf(g, lo), hi);                     // ref's clip
            bad |= (g < 0.0f) | ((g >= 1.0f) & !(edge & (g == hi)));
        }
    }

    float fres = (float)r0 + g;
    if (bad) {   // exact general path (exec-masked off for bench data)
        float f = (float)t + ds[(size_t)(b * TT + t) * NIT] * inv;
        f = fminf(fmaxf(f, 0.0f), (float)(TT - 1));
        for (int i = 1; i < NIT; ++i) {
            int i0 = (int)floorf(f);
            i0 = min(max(i0, 0), TT - 2);
            const float d0 = ds[(size_t)(b * TT + i0) * NIT + i] * inv;
            const float d1 = ds[(size_t)(b * TT + i0 + 1) * NIT + i] * inv;
            const float tf = f - (float)i0;
            f = fminf(fmaxf(f + d0 + tf * (d1 - d0), 0.0f), (float)(TT - 1));
        }
        fres = f;
    }
    f_out[b * TT + t] = fres;
}

// ---------------------------------------------------------------------------
// Kernel 2: Catmull-Rom resampling, 16 consecutive t per block, sliding
// 4-row register window over 19 rows (all loads issued up-front). Fast path
// (i1 == t) is block-uniform; general gather fallback kept for correctness.
// ---------------------------------------------------------------------------
__global__ __launch_bounds__(256) void cubic_kernel(const float* __restrict__ xs,
                                                    const float* __restrict__ f_in,
                                                    float* __restrict__ out) {
    const int blk = blockIdx.x;                  // B * (T/KT) = 2048 blocks
    const int b   = blk >> 6;                    // 64 blocks per b
    const int t0  = (blk & 63) * KT;
    const int tid = threadIdx.x;                 // 256 threads * float4 = D

    const size_t base = (size_t)b * TT * DD / 4; // in float4 units
    const float4* X = (const float4*)xs + base;
    float4* O = (float4*)out + base;

    // all 19 window rows: t0-1 .. t0+17 (clamped)
    float4 w[KT + 3];
#pragma unroll
    for (int r = 0; r < KT + 3; ++r) {
        const int row = min(max(t0 - 1 + r, 0), TT - 1);
        w[r] = X[(size_t)row * (DD / 4) + tid];
    }
    // 16 f values (uniform across block) as 4 broadcast float4 loads
    const float4* fp = (const float4*)(f_in + (size_t)b * TT + t0);
    const float4 fv0 = fp[0], fv1 = fp[1], fv2 = fp[2], fv3 = fp[3];
    const float fvals[KT] = {fv0.x, fv0.y, fv0.z, fv0.w, fv1.x, fv1.y, fv1.z, fv1.w,
                             fv2.x, fv2.y, fv2.z, fv2.w, fv3.x, fv3.y, fv3.z, fv3.w};

#pragma unroll
    for (int k = 0; k < KT; ++k) {
        const int t = t0 + k;
        const float f = fvals[k];
        int i1 = (int)floorf(f);
        i1 = min(max(i1, 0), TT - 1);
        const float tf = f - (float)i1;
        const float t2 = tf * tf, t3 = t2 * tf;
        const float w0 = -0.5f * t3 + t2 - 0.5f * tf;
        const float w1 = 1.5f * t3 - 2.5f * t2 + 1.0f;
        const float w2 = -1.5f * t3 + 2.0f * t2 + 0.5f * tf;
        const float w3 = 0.5f * t3 - 0.5f * t2;

        float4 q0, q1, q2, q3;
        if (i1 == t) {            // block-uniform fast path (always, bench data)
            q0 = w[k]; q1 = w[k + 1]; q2 = w[k + 2]; q3 = w[k + 3];
        } else {                  // general gather fallback (scalar-skipped)
            const int j0 = max(i1 - 1, 0);
            const int j2 = min(i1 + 1, TT - 1);
            const int j3 = min(i1 + 2, TT - 1);
            q0 = X[(size_t)j0 * (DD / 4) + tid];
            q1 = X[(size_t)i1 * (DD / 4) + tid];
            q2 = X[(size_t)j2 * (DD / 4) + tid];
            q3 = X[(size_t)j3 * (DD / 4) + tid];
        }
        float4 v;
        v.x = w0 * q0.x + w1 * q1.x + w2 * q2.x + w3 * q3.x;
        v.y = w0 * q0.y + w1 * q1.y + w2 * q2.y + w3 * q3.y;
        v.z = w0 * q0.z + w1 * q1.z + w2 * q2.z + w3 * q3.z;
        v.w = w0 * q0.w + w1 * q1.w + w2 * q2.w + w3 * q3.w;
        O[(size_t)t * (DD / 4) + tid] = v;
    }
}

extern "C" void kernel_launch(void* const* d_in, const int* in_sizes, int n_in,
                              void* d_out, int out_size, void* d_ws, size_t ws_size,
                              hipStream_t stream) {
    const float* xs = (const float*)d_in[0];   // (B, T, D) f32
    const float* ds = (const float*)d_in[1];   // (B, T, N_ITER) f32

    float* out_ys = (float*)d_out;                     // (B, T, D)
    float* out_f  = out_ys + (size_t)BB * TT * DD;     // (B, T)

    gw_ode_kernel<<<dim3((BB * TT) / K1T), K1T, 0, stream>>>(ds, out_f);
    cubic_kernel<<<dim3(BB * (TT / KT)), 256, 0, stream>>>(xs, out_f, out_ys);
}

// Round 4
// 54.760 us; speedup vs baseline: 2.5839x; 2.5839x over previous
//
#include <hip/hip_runtime.h>

// Problem constants (from reference): B=32, T=1024, D=1024, N_ITER=256, SR=4
#define BB 32
#define TT 1024
#define DD 1024
#define NIT 256
#define SRR 4
#define CS 32            // ODE steps per staged chunk
#define K1T 128          // threads (= t values) per gw_ode block

typedef float vf4 __attribute__((ext_vector_type(4)));   // native vec for nt-store

// ---------------------------------------------------------------------------
// Kernel 1: warp-function ODE. Block = 128 consecutive t of one b.
// Stage ds[b, t0..t0+128, c*32..c*32+31] into LDS (coalesced 128B row-chunks,
// stride-33 padding = conflict-free), register-double-buffered across chunks.
// Fast path keeps g = f - r0 with a single fma + clamp per step; a per-lane
// 'bad' flag falls back to the exact general gather integration (never taken
// for the bench data, exec-mask-skipped).  [~8 us measured in round 2]
// ---------------------------------------------------------------------------
__global__ __launch_bounds__(K1T) void gw_ode_kernel(const float* __restrict__ ds,
                                                     float* __restrict__ f_out) {
    __shared__ float slab[(K1T + 1) * 33];     // [129][33] floats, 17 KB
    const int tid = threadIdx.x;
    const int b   = blockIdx.x >> 3;           // 8 blocks per b
    const int t0  = (blockIdx.x & 7) * K1T;
    const int t   = t0 + tid;
    const int r0  = (t < TT - 2) ? t : (TT - 2);
    const int ia  = r0 - t0;                   // slab row of d0 for this lane
    const float inv = 1.0f / (float)(NIT * SRR);
    const float lo  = -(float)r0;
    const float hi  = (float)(TT - 1 - r0);
    const bool edge = (r0 == TT - 2);

    const float4* dsv = (const float4*)ds;

    float4 buf[2][9];
#pragma unroll
    for (int it = 0; it < 8; ++it) {
        const int p = it * K1T + tid, r = p >> 3, q = p & 7;
        const int row = (t0 + r < TT - 1) ? (t0 + r) : (TT - 1);
        buf[0][it] = dsv[(size_t)(b * TT + row) * (NIT / 4) + q];
    }
    if (tid < 8) {
        const int row = (t0 + K1T < TT - 1) ? (t0 + K1T) : (TT - 1);
        buf[0][8] = dsv[(size_t)(b * TT + row) * (NIT / 4) + tid];
    }

    float g = 0.0f;
    bool bad = false;

#pragma unroll
    for (int c = 0; c < NIT / CS; ++c) {
        if (c > 0) __syncthreads();            // all lanes done with prev slab
#pragma unroll
        for (int it = 0; it < 8; ++it) {
            const int p = it * K1T + tid, r = p >> 3, q = p & 7;
            const float4 v = buf[c & 1][it];
            float* s = slab + r * 33 + q * 4;
            s[0] = v.x; s[1] = v.y; s[2] = v.z; s[3] = v.w;
        }
        if (tid < 8) {
            const float4 v = buf[c & 1][8];
            float* s = slab + K1T * 33 + tid * 4;
            s[0] = v.x; s[1] = v.y; s[2] = v.z; s[3] = v.w;
        }
        __syncthreads();
        if (c < NIT / CS - 1) {                // prefetch next chunk
#pragma unroll
            for (int it = 0; it < 8; ++it) {
                const int p = it * K1T + tid, r = p >> 3, q = p & 7;
                const int row = (t0 + r < TT - 1) ? (t0 + r) : (TT - 1);
                buf[(c + 1) & 1][it] =
                    dsv[(size_t)(b * TT + row) * (NIT / 4) + (c + 1) * (CS / 4) + q];
            }
            if (tid < 8) {
                const int row = (t0 + K1T < TT - 1) ? (t0 + K1T) : (TT - 1);
                buf[(c + 1) & 1][8] =
                    dsv[(size_t)(b * TT + row) * (NIT / 4) + (c + 1) * (CS / 4) + tid];
            }
        }
        int jstart = 0;
        if (c == 0) {
            float f0 = (float)t + slab[tid * 33] * inv;      // ds[b,t,0]
            f0 = fminf(fmaxf(f0, 0.0f), (float)(TT - 1));
            g = f0 - (float)r0;
            jstart = 1;
        }
#pragma unroll 8
        for (int j = jstart; j < CS; ++j) {
            const float d0 = slab[ia * 33 + j] * inv;
            const float d1 = slab[(ia + 1) * 33 + j] * inv;
            g = fmaf(g, 1.0f + (d1 - d0), d0);               // 1-fma chain
            g = fminf(fmaxf(g, lo), hi);                     // ref's clip
            bad |= (g < 0.0f) | ((g >= 1.0f) & !(edge & (g == hi)));
        }
    }

    float fres = (float)r0 + g;
    if (bad) {   // exact general path (exec-masked off for bench data)
        float f = (float)t + ds[(size_t)(b * TT + t) * NIT] * inv;
        f = fminf(fmaxf(f, 0.0f), (float)(TT - 1));
        for (int i = 1; i < NIT; ++i) {
            int i0 = (int)floorf(f);
            i0 = min(max(i0, 0), TT - 2);
            const float d0 = ds[(size_t)(b * TT + i0) * NIT + i] * inv;
            const float d1 = ds[(size_t)(b * TT + i0 + 1) * NIT + i] * inv;
            const float tf = f - (float)i0;
            f = fminf(fmaxf(f + d0 + tf * (d1 - d0), 0.0f), (float)(TT - 1));
        }
        fres = f;
    }
    f_out[b * TT + t] = fres;
}

// ---------------------------------------------------------------------------
// Kernel 2: Catmull-Rom resampling. One block per (b,t) output row (round-1
// structure: 16 VGPR, no spill) + XCD-aware chunked swizzle so the 4
// consecutive-t blocks sharing each input row land on the SAME XCD's L2.
// Output stores are nontemporal (write-once stream).
// ---------------------------------------------------------------------------
__global__ __launch_bounds__(256) void cubic_kernel(const float* __restrict__ xs,
                                                    const float* __restrict__ f_in,
                                                    float* __restrict__ out) {
    // bijective chunked XCD swizzle: nwg = 32768, 8 XCDs, 4096 blocks each
    const int nwg = BB * TT;
    const int bt = (blockIdx.x & 7) * (nwg >> 3) + (blockIdx.x >> 3);
    const int b = bt >> 10;

    const float fv = f_in[bt];
    int i1 = (int)floorf(fv);
    i1 = min(max(i1, 0), TT - 1);
    const float tf = fv - (float)i1;
    const float t2 = tf * tf;
    const float t3 = t2 * tf;
    const float w0 = -0.5f * t3 + t2 - 0.5f * tf;
    const float w1 = 1.5f * t3 - 2.5f * t2 + 1.0f;
    const float w2 = -1.5f * t3 + 2.0f * t2 + 0.5f * tf;
    const float w3 = 0.5f * t3 - 0.5f * t2;

    const int j0 = max(i1 - 1, 0);
    const int j2 = min(i1 + 1, TT - 1);
    const int j3 = min(i1 + 2, TT - 1);

    const size_t base = (size_t)b * TT * DD;
    const float4* r0 = (const float4*)(xs + base + (size_t)j0 * DD);
    const float4* r1 = (const float4*)(xs + base + (size_t)i1 * DD);
    const float4* r2 = (const float4*)(xs + base + (size_t)j2 * DD);
    const float4* r3 = (const float4*)(xs + base + (size_t)j3 * DD);
    vf4* o = (vf4*)(out + (size_t)bt * DD);

    const int d = threadIdx.x;            // 256 threads * float4 = 1024
    const float4 p0 = r0[d];
    const float4 p1 = r1[d];
    const float4 p2 = r2[d];
    const float4 p3 = r3[d];
    vf4 v;
    v.x = w0 * p0.x + w1 * p1.x + w2 * p2.x + w3 * p3.x;
    v.y = w0 * p0.y + w1 * p1.y + w2 * p2.y + w3 * p3.y;
    v.z = w0 * p0.z + w1 * p1.z + w2 * p2.z + w3 * p3.z;
    v.w = w0 * p0.w + w1 * p1.w + w2 * p2.w + w3 * p3.w;
    __builtin_nontemporal_store(v, &o[d]);
}

extern "C" void kernel_launch(void* const* d_in, const int* in_sizes, int n_in,
                              void* d_out, int out_size, void* d_ws, size_t ws_size,
                              hipStream_t stream) {
    const float* xs = (const float*)d_in[0];   // (B, T, D) f32
    const float* ds = (const float*)d_in[1];   // (B, T, N_ITER) f32

    float* out_ys = (float*)d_out;                     // (B, T, D)
    float* out_f  = out_ys + (size_t)BB * TT * DD;     // (B, T)

    gw_ode_kernel<<<dim3((BB * TT) / K1T), K1T, 0, stream>>>(ds, out_f);
    cubic_kernel<<<dim3(BB * TT), 256, 0, stream>>>(xs, out_f, out_ys);
}